// Round 2
// baseline (863.591 us; speedup 1.0000x reference)
//
#include <hip/hip_runtime.h>

// SymplecticLayer: 2 leapfrog steps, force = grad of tanh-MLP Hamiltonian (8->128->128->1).
// Round 2: operand-swapped fp8 MFMA (weights in A-frag, activations in B-frag,
// D[m=feature][n=batch]). Layout transform between layers = 16 conflict-free
// ds_bpermute + 8 cndmask (no LDS act buffer, no byte stores). State in registers
// (qd0 lanes: p, qd1 lanes: q). b1 folded into MFMA K-pad row; w3*128 folded into
// backward W2 copy; forward W2 scaled by 8 (folded into exp2-arg FMA); sech^2
// computed directly from e (no h2 tanh). LDS 39,424 B -> 4 blocks/CU.

typedef float f32x4 __attribute__((ext_vector_type(4)));

#define DT   0.01f
#define L2E2 2.8853901f   // 2*log2(e)

__device__ __forceinline__ int bperm(int idx, int v) {
    return __builtin_amdgcn_ds_bpermute(idx, v);
}
__device__ __forceinline__ int pack4(float a, float b, float c, float d) {
    int v = __builtin_amdgcn_cvt_pk_fp8_f32(a, b, 0, false);
    v = __builtin_amdgcn_cvt_pk_fp8_f32(c, d, v, true);
    return v;
}
__device__ __forceinline__ unsigned char to_fp8(float x) {
    return (unsigned char)(__builtin_amdgcn_cvt_pk_fp8_f32(x, x, 0, false) & 0xff);
}

// C-layout packed dwords (pk[nt] = features nt*16+qd*4+0..3 of batch c) ->
// B-frags (bf[kt] = bytes k=kt*32+qd*8+0..7 of batch c).
__device__ __forceinline__ void xform(const int* pk, long long* bf,
                                      int idx_lo, int idx_hi, int qd) {
    #pragma unroll
    for (int kt = 0; kt < 4; kt++) {
        int la = bperm(idx_lo, pk[2 * kt]);
        int lb = bperm(idx_lo, pk[2 * kt + 1]);
        int ha = bperm(idx_hi, pk[2 * kt]);
        int hb = bperm(idx_hi, pk[2 * kt + 1]);
        int lo = (qd < 2) ? la : lb;
        int hi = (qd < 2) ? ha : hb;
        bf[kt] = (((long long)(unsigned)hi) << 32) | (unsigned)lo;
    }
}

__global__ __launch_bounds__(256, 4) void hnn_kernel(
    const float* __restrict__ Z, const float* __restrict__ W1,
    const float* __restrict__ B1, const float* __restrict__ W2,
    const float* __restrict__ B2, const float* __restrict__ W3,
    float* __restrict__ OUT)
{
    // ---- LDS: 4096+16384+16384+2048+512 = 39,424 B -> 4 blocks/CU ----
    __shared__ __align__(16) unsigned char sW1A[4096];    // fwd A = W1^T (m=f, k=i; k=8 -> b1)
    __shared__ __align__(16) unsigned char sW2F[16384];   // fwd A = 8*W2^T (m=k2, k=j)
    __shared__ __align__(16) unsigned char sW2R[16384];   // bwd A = 128*w3(.)W2 (m=j, k=k2)
    __shared__ __align__(16) unsigned char sW1R[2048];    // bwd A = W1 (m=i pad16, k=f)
    __shared__ __align__(16) float sB2[128];              // b2 * 2log2e

    const int t = threadIdx.x, blk = blockIdx.x;

    for (int i = t; i < 1024; i += 256) ((int*)sW1A)[i] = 0;
    for (int i = t; i < 512;  i += 256) ((int*)sW1R)[i] = 0;
    __syncthreads();

    // W1 (8x128, row-major [i][f])
    for (int i = t; i < 1024; i += 256) {
        int i8 = i >> 7, f = i & 127;
        unsigned char q = to_fp8(W1[i]);
        sW1A[(f >> 4) * 512 + (f & 15) * 8 + i8] = q;
        sW1R[(f >> 5) * 512 + (i8 | (((f >> 3) & 3) << 4)) * 8 + (f & 7)] = q;
    }
    if (t < 128) {
        sW1A[(t >> 4) * 512 + ((t & 15) + 16) * 8] = to_fp8(B1[t]);  // bias row k=8
        sB2[t] = B2[t] * L2E2;
    }
    // W2 (128x128, row-major [j][k2])
    for (int i = t; i < 4096; i += 256) {
        f32x4 w  = ((const f32x4*)W2)[i];
        f32x4 w3 = *(const f32x4*)(W3 + ((i * 4) & 127));
        int j = (i * 4) >> 7, k0 = (i * 4) & 127;
        #pragma unroll
        for (int u = 0; u < 4; u++) {
            int k2 = k0 + u;
            sW2F[(((k2 >> 4) << 2) | (j >> 5)) * 512
                 + ((k2 & 15) | (((j >> 3) & 3) << 4)) * 8 + (j & 7)] = to_fp8(w[u] * 8.0f);
            sW2R[(((j >> 4) << 2) | (k2 >> 5)) * 512
                 + ((j & 15) | (((k2 >> 3) & 3) << 4)) * 8 + (k2 & 7)] = to_fp8(w[u] * w3[u] * 128.0f);
        }
    }
    __syncthreads();
    // No further barriers: everything below is wave-local.

    const int lane = t & 63, wv = t >> 6;
    const int c = lane & 15, qd = lane >> 4;
    const int laneB = lane * 8;
    const int idx_pt = (lane ^ 16) << 2;
    const int idx_lo = ((((2 * qd) & 3) << 4) | c) << 2;
    const int idx_hi = (((((2 * qd) | 1) & 3) << 4) | c) << 2;
    const int row = blk * 64 + wv * 16 + c;
    const float cp  = (qd == 0) ? (-0.5f * DT / 64.0f) : 0.0f;  // p -= 0.5*DT*dHdq (acc scale 64)
    const float cqb = (qd == 1) ? (DT / 64.0f) : 0.0f;          // q += DT*dHdp (even evs)

    // state: qd0 lanes hold p[c][0..3], qd1 lanes hold q[c][0..3] (qd2/3: dup of p/q, unused)
    f32x4 st = *(const f32x4*)(Z + row * 8 + ((qd & 1) ? 0 : 4));

    float uarr[8][4];   // 1 - h1^2, C-layout
    int pk[8];
    long long bf[4];

    #pragma unroll 1
    for (int ev = 0; ev < 4; ev++) {
        // ---- build z B-frag: k=0..7 = (q,p), k=8 = 1.0 (bias row) ----
        int own = pack4(st[0], st[1], st[2], st[3]);
        int oth = bperm(idx_pt, own);
        int zlo = (qd == 0) ? oth : ((qd == 1) ? 0x38 : 0);   // 0x38 = e4m3(1.0)
        int zhi = (qd == 0) ? own : 0;
        long long zB = (((long long)(unsigned)zhi) << 32) | (unsigned)zlo;

        // ---- L1 fwd: h1 = tanh(z@W1 + b1), keep u = 1-h1^2 ----
        #pragma unroll
        for (int nt = 0; nt < 8; nt++) {
            long long a = *(const long long*)(sW1A + nt * 512 + laneB);
            f32x4 acc = __builtin_amdgcn_mfma_f32_16x16x32_fp8_fp8(
                a, zB, (f32x4){0.f, 0.f, 0.f, 0.f}, 0, 0, 0);
            float h[4];
            #pragma unroll
            for (int r = 0; r < 4; r++) {
                float e  = __builtin_amdgcn_exp2f(acc[r] * L2E2);
                float rc = __builtin_amdgcn_rcpf(1.0f + e);
                float hh = 1.0f - 2.0f * rc;
                h[r] = hh;
                uarr[nt][r] = __builtin_fmaf(-hh, hh, 1.0f);
            }
            pk[nt] = pack4(h[0], h[1], h[2], h[3]);
        }
        xform(pk, bf, idx_lo, idx_hi, qd);

        // ---- L2 fwd: d2' = 16*sech^2(h1@W2 + b2)  (w3 folded into sW2R) ----
        #pragma unroll
        for (int nt = 0; nt < 8; nt++) {
            f32x4 b2c = *(const f32x4*)(sB2 + nt * 16 + qd * 4);
            f32x4 acc = {0.f, 0.f, 0.f, 0.f};
            #pragma unroll
            for (int kt = 0; kt < 4; kt++) {
                long long a = *(const long long*)(sW2F + (nt * 4 + kt) * 512 + laneB);
                acc = __builtin_amdgcn_mfma_f32_16x16x32_fp8_fp8(a, bf[kt], acc, 0, 0, 0);
            }
            float d2[4];
            #pragma unroll
            for (int r = 0; r < 4; r++) {
                float arg = __builtin_fmaf(acc[r], 0.36067376f, b2c[r]);  // 2log2e*(acc/8 + b2)
                arg = fminf(arg, 126.0f);                                  // overflow guard
                float e  = __builtin_amdgcn_exp2f(arg);
                float rc = __builtin_amdgcn_rcpf(1.0f + e);
                d2[r] = 64.0f * (e * rc) * rc;                             // 16 * 4e/(1+e)^2
            }
            pk[nt] = pack4(d2[0], d2[1], d2[2], d2[3]);
        }
        xform(pk, bf, idx_lo, idx_hi, qd);

        // ---- L2 bwd: d1 = u .* (d2' @ (128*w3.W2)^T) / 32  (net scale 64) ----
        #pragma unroll
        for (int nt = 0; nt < 8; nt++) {
            f32x4 acc = {0.f, 0.f, 0.f, 0.f};
            #pragma unroll
            for (int kt = 0; kt < 4; kt++) {
                long long a = *(const long long*)(sW2R + (nt * 4 + kt) * 512 + laneB);
                acc = __builtin_amdgcn_mfma_f32_16x16x32_fp8_fp8(a, bf[kt], acc, 0, 0, 0);
            }
            float d1[4];
            #pragma unroll
            for (int r = 0; r < 4; r++)
                d1[r] = (acc[r] * uarr[nt][r]) * 0.03125f;
            pk[nt] = pack4(d1[0], d1[1], d1[2], d1[3]);
        }
        xform(pk, bf, idx_lo, idx_hi, qd);

        // ---- L1 bwd: g = d1 @ W1^T (rows m=0..3 dHdq -> qd0, m=4..7 dHdp -> qd1) ----
        f32x4 g = {0.f, 0.f, 0.f, 0.f};
        #pragma unroll
        for (int kt = 0; kt < 4; kt++) {
            long long a = *(const long long*)(sW1R + kt * 512 + laneB);
            g = __builtin_amdgcn_mfma_f32_16x16x32_fp8_fp8(a, bf[kt], g, 0, 0, 0);
        }
        float coef = cp + ((ev & 1) ? 0.0f : cqb);
        #pragma unroll
        for (int r = 0; r < 4; r++) st[r] = __builtin_fmaf(coef, g[r], st[r]);
    }

    if (qd < 2) *(f32x4*)(OUT + row * 8 + ((qd & 1) ? 0 : 4)) = st;
}

extern "C" void kernel_launch(void* const* d_in, const int* in_sizes, int n_in,
                              void* d_out, int out_size, void* d_ws, size_t ws_size,
                              hipStream_t stream) {
    const float* Z  = (const float*)d_in[0];
    const float* W1 = (const float*)d_in[1];
    const float* B1 = (const float*)d_in[2];
    const float* W2 = (const float*)d_in[3];
    const float* B2 = (const float*)d_in[4];
    const float* W3 = (const float*)d_in[5];
    float* OUT = (float*)d_out;
    int blocks = in_sizes[0] / 512;   // 64 batch rows per block
    hipLaunchKernelGGL(hnn_kernel, dim3(blocks), dim3(256), 0, stream,
                       Z, W1, B1, W2, B2, W3, OUT);
}